// Round 1
// baseline (392.923 us; speedup 1.0000x reference)
//
#include <hip/hip_runtime.h>

#define HH 1024
#define AA 512
#define BB 32
#define SS 1024
#define TN 1024
#define M_ENC (SS*BB)
#define M_TOT ((SS+TN)*BB)
#define NCH 8

typedef __attribute__((ext_vector_type(8))) short short8;
typedef __attribute__((ext_vector_type(4))) float f4;

__device__ __forceinline__ unsigned int f2bf_pk(float a, float b) {
  unsigned int ua = __float_as_uint(a); ua = (ua + 0x7fffu + ((ua >> 16) & 1u)) >> 16;
  unsigned int ub = __float_as_uint(b); ub = (ub + 0x7fffu + ((ub >> 16) & 1u)) >> 16;
  return ua | (ub << 16);
}

// ---------------- big fused GEMM: e1[row] = sum_a V[a]*tanh( X[row,:] . W[a,:] ) ----------------
// rows 0..32767: X=enc, W=W1, V=W4[0:512]; rows 32768..65535: X=h0, W=W5, V=W8[0:512]
__global__ __launch_bounds__(512, 4)
void big_e1(const float* __restrict__ enc, const float* __restrict__ h0,
            const float* __restrict__ W1, const float* __restrict__ W5,
            const float* __restrict__ W4, const float* __restrict__ W8,
            float* __restrict__ e1) {
  const int wg   = blockIdx.x;        // 1024 blocks, 64 rows each
  const int tid  = threadIdx.x;       // 512
  const int lane = tid & 63;
  const int wave = tid >> 6;          // 0..7
  const int rowg = wave >> 2;         // 0..1  (32-row group)
  const int colg = wave & 3;          // 0..3  (128-col group)
  const int l15  = lane & 15;
  const int lg   = lane >> 4;         // 0..3

  const bool is_enc = (wg * 64) < M_ENC;
  const float* __restrict__ Xg = is_enc ? enc : h0;
  const float* __restrict__ Wg = is_enc ? W1 : W5;
  const float* __restrict__ Vg = is_enc ? W4 : W8;
  const int row0 = is_enc ? wg * 64 : wg * 64 - M_ENC;

  __shared__ unsigned short lx[64][40];    // X tile, padded stride 80B
  __shared__ unsigned short lw[512][40];   // W tile
  __shared__ float lred[4][64];

  float vv[8];
#pragma unroll
  for (int cf = 0; cf < 8; ++cf) vv[cf] = Vg[colg * 128 + cf * 16 + l15];

  f4 acc[2][8];
#pragma unroll
  for (int i = 0; i < 2; ++i)
#pragma unroll
    for (int j = 0; j < 8; ++j) acc[i][j] = (f4){0.f, 0.f, 0.f, 0.f};

  const int sr = tid >> 3;            // 0..63
  const int sk = (tid & 7) * 4;       // 0..28
  const float* __restrict__ xsrc = Xg + (size_t)(row0 + sr) * HH + sk;
  const float* __restrict__ wsrc = Wg + (size_t)sr * HH + sk;

  for (int k0 = 0; k0 < HH; k0 += 32) {
    // stage X: 64 rows x 32 k (fp32 -> bf16)
    f4 xv = *(const f4*)(xsrc + k0);
    uint2 px;
    px.x = f2bf_pk(xv[0], xv[1]);
    px.y = f2bf_pk(xv[2], xv[3]);
    *(uint2*)&lx[sr][sk] = px;
    // stage W: 512 rows x 32 k over 8 passes
#pragma unroll
    for (int p = 0; p < 8; ++p) {
      f4 wv = *(const f4*)(wsrc + (size_t)p * 64 * HH + k0);
      uint2 pw;
      pw.x = f2bf_pk(wv[0], wv[1]);
      pw.y = f2bf_pk(wv[2], wv[3]);
      *(uint2*)&lw[p * 64 + sr][sk] = pw;
    }
    __syncthreads();
    const int koff = lg * 8;
    short8 a0 = *(const short8*)&lx[rowg * 32 + l15][koff];
    short8 a1 = *(const short8*)&lx[rowg * 32 + 16 + l15][koff];
#pragma unroll
    for (int cf = 0; cf < 8; ++cf) {
      short8 bf = *(const short8*)&lw[colg * 128 + cf * 16 + l15][koff];
      acc[0][cf] = __builtin_amdgcn_mfma_f32_16x16x32_bf16(a0, bf, acc[0][cf], 0, 0, 0);
      acc[1][cf] = __builtin_amdgcn_mfma_f32_16x16x32_bf16(a1, bf, acc[1][cf], 0, 0, 0);
    }
    __syncthreads();
  }

  // epilogue: tanh, weight by V, reduce over this wave's 128 cols, then across col-groups
#pragma unroll
  for (int rf = 0; rf < 2; ++rf) {
    float ps[4] = {0.f, 0.f, 0.f, 0.f};
#pragma unroll
    for (int cf = 0; cf < 8; ++cf) {
      float w = vv[cf];
#pragma unroll
      for (int r = 0; r < 4; ++r) ps[r] += w * tanhf(acc[rf][cf][r]);
    }
#pragma unroll
    for (int r = 0; r < 4; ++r) {
#pragma unroll
      for (int off = 1; off < 16; off <<= 1) ps[r] += __shfl_xor(ps[r], off);
    }
    if (l15 == 0) {
#pragma unroll
      for (int r = 0; r < 4; ++r)
        lred[colg][rowg * 32 + rf * 16 + lg * 4 + r] = ps[r];
    }
  }
  __syncthreads();
  if (tid < 64) {
    float s = lred[0][tid] + lred[1][tid] + lred[2][tid] + lred[3][tid];
    e1[(size_t)wg * 64 + tid] = s;
  }
}

// ---------------- exi full logits: exf[b][s] = e1[s*B+b] + sum_a W4[2A+a]*tanh(ax[b,s]*W3[a]) ----
__global__ void exf_kernel(const float* __restrict__ e1, const float* __restrict__ ax,
                           const float* __restrict__ W3, const float* __restrict__ W4,
                           float* __restrict__ exf) {
  __shared__ float w3s[AA], w4r[AA];
  const int tid = threadIdx.x;  // 256
  for (int i = tid; i < AA; i += 256) { w3s[i] = W3[i]; w4r[i] = W4[2 * AA + i]; }
  __syncthreads();
  const int b = blockIdx.x >> 2;
  const int s = (blockIdx.x & 3) * 256 + tid;
  const float x = ax[b * SS + s];
  float er = 0.f;
#pragma unroll 8
  for (int a = 0; a < AA; ++a) er += w4r[a] * tanhf(x * w3s[a]);
  exf[b * SS + s] = e1[s * BB + b] + er;
}

// ---------------- softmax over s (contiguous rows) + ax_new output ----------------
__global__ void softmax_bs(const float* __restrict__ ein, const float* __restrict__ ax,
                           float* __restrict__ wout, float* __restrict__ axnew) {
  const int b = blockIdx.x, tid = threadIdx.x;  // 256 threads, 1024 elems
  __shared__ float red[256];
  float loc[4];
  float m = -1e30f;
#pragma unroll
  for (int i = 0; i < 4; ++i) { loc[i] = ein[b * SS + i * 256 + tid]; m = fmaxf(m, loc[i]); }
  red[tid] = m; __syncthreads();
  for (int off = 128; off > 0; off >>= 1) {
    if (tid < off) red[tid] = fmaxf(red[tid], red[tid + off]);
    __syncthreads();
  }
  m = red[0]; __syncthreads();
  float sum = 0.f;
#pragma unroll
  for (int i = 0; i < 4; ++i) { loc[i] = __expf(loc[i] - m); sum += loc[i]; }
  red[tid] = sum; __syncthreads();
  for (int off = 128; off > 0; off >>= 1) {
    if (tid < off) red[tid] += red[tid + off];
    __syncthreads();
  }
  const float inv = 1.f / red[0];
#pragma unroll
  for (int i = 0; i < 4; ++i) {
    const int s = i * 256 + tid;
    const float a_ = loc[i] * inv;
    wout[b * SS + s] = a_;
    axnew[b * SS + s] = ax[b * SS + s] + a_;
  }
}

// ---------------- softmax over t, input layout [t][b] strided ----------------
__global__ void softmax_tb(const float* __restrict__ ein, float* __restrict__ wout) {
  const int b = blockIdx.x, tid = threadIdx.x;
  __shared__ float red[256];
  float loc[4];
  float m = -1e30f;
#pragma unroll
  for (int i = 0; i < 4; ++i) { loc[i] = ein[(i * 256 + tid) * BB + b]; m = fmaxf(m, loc[i]); }
  red[tid] = m; __syncthreads();
  for (int off = 128; off > 0; off >>= 1) {
    if (tid < off) red[tid] = fmaxf(red[tid], red[tid + off]);
    __syncthreads();
  }
  m = red[0]; __syncthreads();
  float sum = 0.f;
#pragma unroll
  for (int i = 0; i < 4; ++i) { loc[i] = __expf(loc[i] - m); sum += loc[i]; }
  red[tid] = sum; __syncthreads();
  for (int off = 128; off > 0; off >>= 1) {
    if (tid < off) red[tid] += red[tid + off];
    __syncthreads();
  }
  const float inv = 1.f / red[0];
#pragma unroll
  for (int i = 0; i < 4; ++i) wout[b * TN + (i * 256 + tid)] = loc[i] * inv;
}

// ---------------- chunked weighted sum: part[b][ch][h] = sum_{s in ch} w[b,s]*X[s,b,h] ------------
__global__ void wpart(const float* __restrict__ X, const float* __restrict__ w,
                      float* __restrict__ part) {
  const int b = blockIdx.x / NCH, ch = blockIdx.x % NCH;
  const int tid = threadIdx.x;  // 256, each handles 4 h
  __shared__ float ws[SS / NCH];
  if (tid < SS / NCH) ws[tid] = w[b * SS + ch * (SS / NCH) + tid];
  __syncthreads();
  f4 acc = (f4){0.f, 0.f, 0.f, 0.f};
  const float* base = X + ((size_t)(ch * (SS / NCH)) * BB + b) * HH + tid * 4;
  for (int i = 0; i < SS / NCH; ++i) {
    f4 x = *(const f4*)(base + (size_t)i * BB * HH);
    acc += ws[i] * x;
  }
  *(f4*)&part[((size_t)(b * NCH + ch)) * HH + tid * 4] = acc;
}

__global__ void wreduce(const float* __restrict__ part, float* __restrict__ out) {
  const int idx = blockIdx.x * 256 + threadIdx.x;  // over B*H
  const int b = idx / HH, h = idx % HH;
  float s = 0.f;
#pragma unroll
  for (int ch = 0; ch < NCH; ++ch) s += part[((size_t)(b * NCH + ch)) * HH + h];
  out[idx] = s;
}

// ---------------- zi[b] = sigmoid( cxi[b,:].W11[0:H] + cti[b,:].W11[H:2H] ) ----------------
__global__ void zi_kernel(const float* __restrict__ cxi, const float* __restrict__ cti,
                          const float* __restrict__ W11, float* __restrict__ zi) {
  const int b = blockIdx.x, tid = threadIdx.x;  // 256
  float s = 0.f;
  for (int i = tid; i < HH; i += 256) s += cxi[b * HH + i] * W11[i] + cti[b * HH + i] * W11[HH + i];
  __shared__ float red[4];
  for (int off = 32; off > 0; off >>= 1) s += __shfl_down(s, off);
  if ((tid & 63) == 0) red[tid >> 6] = s;
  __syncthreads();
  if (tid == 0) {
    float t = red[0] + red[1] + red[2] + red[3];
    zi[b] = 1.f / (1.f + __expf(-t));
  }
}

// ---------------- ci[b,h] = z*tanh(cxi.W9[h,:]) + (1-z)*tanh(cti.W10[h,:]) ----------------
__global__ void ci_kernel(const float* __restrict__ cxi, const float* __restrict__ cti,
                          const float* __restrict__ W9, const float* __restrict__ W10,
                          const float* __restrict__ zi, float* __restrict__ out_ci) {
  const int b = blockIdx.x >> 2, hb = blockIdx.x & 3, tid = threadIdx.x;
  const int h = hb * 256 + tid;
  __shared__ float cx[HH], ct[HH];
  for (int i = tid; i < HH; i += 256) { cx[i] = cxi[b * HH + i]; ct[i] = cti[b * HH + i]; }
  __syncthreads();
  const float* __restrict__ w9r  = W9  + (size_t)h * HH;
  const float* __restrict__ w10r = W10 + (size_t)h * HH;
  float gx = 0.f, gt = 0.f;
  for (int k = 0; k < HH; k += 4) {
    f4 a = *(const f4*)(w9r + k);
    f4 c = *(const f4*)(w10r + k);
    gx += cx[k] * a[0] + cx[k + 1] * a[1] + cx[k + 2] * a[2] + cx[k + 3] * a[3];
    gt += ct[k] * c[0] + ct[k + 1] * c[1] + ct[k + 2] * c[2] + ct[k + 3] * c[3];
  }
  const float z = zi[b];
  out_ci[b * HH + h] = z * tanhf(gx) + (1.f - z) * tanhf(gt);
}

extern "C" void kernel_launch(void* const* d_in, const int* in_sizes, int n_in,
                              void* d_out, int out_size, void* d_ws, size_t ws_size,
                              hipStream_t stream) {
  const float* enc = (const float*)d_in[1];
  const float* h0  = (const float*)d_in[2];
  const float* ax  = (const float*)d_in[3];
  const float* W1  = (const float*)d_in[4];
  const float* W3  = (const float*)d_in[6];
  const float* W4  = (const float*)d_in[7];
  const float* W5  = (const float*)d_in[8];
  const float* W8  = (const float*)d_in[11];
  const float* W9  = (const float*)d_in[12];
  const float* W10 = (const float*)d_in[13];
  const float* W11 = (const float*)d_in[14];
  float* out = (float*)d_out;  // [0:B*H) ci, [B*H : 2*B*H) ax_new

  float* w     = (float*)d_ws;
  float* e1    = w;                 // 65536
  float* exf   = w + 65536;         // 32768
  float* axi   = w + 98304;         // 32768
  float* ati   = w + 131072;        // 32768
  float* cxi   = w + 163840;        // 32768
  float* cti   = w + 196608;        // 32768
  float* zi    = w + 229376;        // 32
  float* partx = w + 229408;        // B*NCH*H = 262144
  float* partt = w + 491552;        // 262144

  big_e1<<<M_TOT / 64, 512, 0, stream>>>(enc, h0, W1, W5, W4, W8, e1);
  exf_kernel<<<BB * 4, 256, 0, stream>>>(e1, ax, W3, W4, exf);
  softmax_bs<<<BB, 256, 0, stream>>>(exf, ax, axi, out + BB * HH);
  softmax_tb<<<BB, 256, 0, stream>>>(e1 + M_ENC, ati);
  wpart<<<BB * NCH, 256, 0, stream>>>(enc, axi, partx);
  wpart<<<BB * NCH, 256, 0, stream>>>(h0, ati, partt);
  wreduce<<<BB * HH / 256, 256, 0, stream>>>(partx, cxi);
  wreduce<<<BB * HH / 256, 256, 0, stream>>>(partt, cti);
  zi_kernel<<<BB, 256, 0, stream>>>(cxi, cti, W11, zi);
  ci_kernel<<<BB * 4, 256, 0, stream>>>(cxi, cti, W9, W10, zi, out);
}